// Round 7
// baseline (868.463 us; speedup 1.0000x reference)
//
#include <hip/hip_runtime.h>
#include <hip/hip_bf16.h>
#include <stdint.h>

#define DEV __device__ __forceinline__

typedef __attribute__((ext_vector_type(8))) short short8;
typedef __attribute__((ext_vector_type(4))) float f32x4;

#define B_ 2
#define S_ 4096
#define E_ 2048
#define H_ 16
#define D_ 128

DEV unsigned short f2bf(float x) {
  union { float f; uint32_t u; } a; a.f = x;
  uint32_t r = a.u + 0x7fffu + ((a.u >> 16) & 1u);
  return (unsigned short)(r >> 16);
}

DEV unsigned int cvt_pk_bf16(float a, float b) {
  unsigned int r;
  asm("v_cvt_pk_bf16_f32 %0, %1, %2" : "=v"(r) : "v"(a), "v"(b));
  return r;
}

DEV float exp2f_(float x) { return __builtin_amdgcn_exp2f(x); }

DEV void glds16(const void* g, void* l) {
  __builtin_amdgcn_global_load_lds(
      (const __attribute__((address_space(1))) uint32_t*)g,
      (__attribute__((address_space(3))) uint32_t*)l, 16, 0, 0);
}

__global__ __launch_bounds__(256) void cvtk(const float* __restrict__ in,
                                            unsigned short* __restrict__ out, int n4) {
  int i = blockIdx.x * blockDim.x + threadIdx.x;
  int stride = gridDim.x * blockDim.x;
  for (; i < n4; i += stride) {
    float4 v = ((const float4*)in)[i];
    ushort4 o;
    o.x = f2bf(v.x); o.y = f2bf(v.y); o.z = f2bf(v.z); o.w = f2bf(v.w);
    ((ushort4*)out)[i] = o;
  }
}

// C = A(MxK) * B(NxK)^T ; all bf16 inputs, fp32 accumulate.
template<int OUT_F32>
__global__ __launch_bounds__(256) void gemm_nt(
    const unsigned short* __restrict__ A,
    const unsigned short* __restrict__ Bm,
    void* __restrict__ Cp,
    const float* __restrict__ bias,
    int M, int N, int K, int nbn)
{
  __shared__ __align__(16) unsigned char lA[128 * 64];
  __shared__ __align__(16) unsigned char lB[128 * 64];
  int bid = blockIdx.x;
  int bm = bid / nbn, bn = bid % nbn;
  int t = threadIdx.x;
  int lane = t & 63, wv = t >> 6;
  int hi = lane >> 4, lo = lane & 15;
  int wm = wv >> 1, wn = wv & 1;
  int m0 = bm * 128, n0 = bn * 128;

  f32x4 acc[4][4] = {};

  for (int k0 = 0; k0 < K; k0 += 32) {
#pragma unroll
    for (int i = 0; i < 2; ++i) {
      int slot = i * 256 + t;
      int row = slot >> 2, c = slot & 3;
      int lbase = (i * 256 + wv * 64) * 16;
      glds16(A + (size_t)(m0 + row) * K + k0 + c * 8, lA + lbase);
      glds16(Bm + (size_t)(n0 + row) * K + k0 + c * 8, lB + lbase);
    }
    __syncthreads();
    short8 af[4], bfr[4];
#pragma unroll
    for (int mi = 0; mi < 4; ++mi)
      af[mi] = *(const short8*)(lA + (wm * 64 + mi * 16 + lo) * 64 + hi * 16);
#pragma unroll
    for (int nj = 0; nj < 4; ++nj)
      bfr[nj] = *(const short8*)(lB + (wn * 64 + nj * 16 + lo) * 64 + hi * 16);
#pragma unroll
    for (int mi = 0; mi < 4; ++mi)
#pragma unroll
      for (int nj = 0; nj < 4; ++nj)
        acc[mi][nj] = __builtin_amdgcn_mfma_f32_16x16x32_bf16(af[mi], bfr[nj], acc[mi][nj], 0, 0, 0);
    __syncthreads();
  }

  if constexpr (OUT_F32) {
    float* C = (float*)Cp;
#pragma unroll
    for (int mi = 0; mi < 4; ++mi)
#pragma unroll
      for (int nj = 0; nj < 4; ++nj) {
        int row = m0 + wm * 64 + mi * 16 + hi * 4;
        int col = n0 + wn * 64 + nj * 16 + lo;
        float bv = bias[col];
#pragma unroll
        for (int r = 0; r < 4; ++r)
          C[(size_t)(row + r) * N + col] = acc[mi][nj][r] + bv;
      }
  } else {
    unsigned short* C = (unsigned short*)Cp;
#pragma unroll
    for (int mi = 0; mi < 4; ++mi)
#pragma unroll
      for (int nj = 0; nj < 4; ++nj) {
        int row = m0 + wm * 64 + mi * 16 + hi * 4;
        int col = n0 + wn * 64 + nj * 16 + lo;
#pragma unroll
        for (int r = 0; r < 4; ++r)
          C[(size_t)(row + r) * N + col] = f2bf(acc[mi][nj][r]);
      }
  }
}

// vt[b,h,d,s] = qkv[b,s,2,h,d]
__global__ __launch_bounds__(256) void transpose_v(const unsigned short* __restrict__ qkv,
                                                   unsigned short* __restrict__ vt) {
  __shared__ __align__(16) unsigned char tl[32768];
  int bid = blockIdx.x;
  int st = bid & 31, bh = bid >> 5;
  int h = bh & 15, b = bh >> 4;
  int s0 = st * 128;
  int t = threadIdx.x, c = t & 15, rr = t >> 4;
#pragma unroll
  for (int i = 0; i < 8; ++i) {
    int s = rr + i * 16;
    const unsigned short* g = qkv + ((((size_t)b * S_ + s0 + s) * 3 + 2) * H_ + h) * D_ + c * 8;
    *(uint4*)(tl + s * 256 + ((c * 16) ^ (((s >> 3) & 7) << 4))) = *(const uint4*)g;
  }
  __syncthreads();
#pragma unroll
  for (int i = 0; i < 8; ++i) {
    int d = rr + i * 16;
    unsigned int w[4];
#pragma unroll
    for (int jj = 0; jj < 4; ++jj) {
      int s_a = c * 8 + jj * 2;
      unsigned int u0 = *(const unsigned short*)(tl + s_a * 256 + ((d * 2) ^ ((c & 7) << 4)));
      unsigned int u1 = *(const unsigned short*)(tl + (s_a + 1) * 256 + ((d * 2) ^ ((c & 7) << 4)));
      w[jj] = u0 | (u1 << 16);
    }
    uint4 val; val.x = w[0]; val.y = w[1]; val.z = w[2]; val.w = w[3];
    unsigned short* g = vt + (((size_t)b * H_ + h) * D_ + d) * S_ + s0 + c * 8;
    *(uint4*)g = val;
  }
}

// Flash attention, reference's extra l_ij semantics, KV block = 128.
// 8 waves x 32 q rows = 256-q block. PV DEFERRED by one tile: iter j runs
// QK(j) then {PV(j-1) [MFMA+LDS] || softmax(j) [VALU]} in one scheduling
// region. P stays in REGISTERS via permlane swaps (no P LDS traffic).
// LDS: K 32K | V0 32K | V1 32K = 96K. 2 barriers/iter.
__global__ __launch_bounds__(512, 2) void attn_fwd(
    const unsigned short* __restrict__ qkv,  // [B,S,3,H,D] bf16
    const unsigned short* __restrict__ vt,   // [B,H,D,S] bf16
    unsigned short* __restrict__ abuf)       // [B,S,H*D] bf16
{
  __shared__ __align__(16) unsigned char lds[98304];
  unsigned char* lK = lds;  // K tile (single-buffered)

  // XCD-chunked swizzle: 512 blocks, 8 XCDs, 64 consecutive logical blocks per
  // XCD -> the 16 q-blocks sharing one (b,h)'s K/V land on the same XCD's L2.
  int bid = (blockIdx.x & 7) * 64 + (blockIdx.x >> 3);
  int qb = bid & 15, bh = bid >> 4;
  int h = bh & 15, b = bh >> 4;
  int t = threadIdx.x, lane = t & 63, wv = t >> 6;
  int hi = lane >> 4, lo = lane & 15;
  int q0 = qb * 256;
  const float c1 = 0.12751744f;  // (1/sqrt(128)) * log2(e)

  // Q fragments: 2 q sub-tiles (B-operand: col = q, k = d)
  short8 qf[2][4];
#pragma unroll
  for (int qj = 0; qj < 2; ++qj) {
    const unsigned short* qbase =
        qkv + ((((size_t)b * S_ + q0 + wv * 32 + qj * 16 + lo) * 3 + 0) * H_ + h) * D_;
#pragma unroll
    for (int ks = 0; ks < 4; ++ks)
      qf[qj][ks] = *(const short8*)(qbase + ks * 32 + hi * 8);
  }

  // staging pointers (pre-swizzled sources, linear LDS dest)
  const unsigned char* gk[4];
  const unsigned char* gv[4];
  int lbs[4];
  {
    int c = t & 15;
#pragma unroll
    for (int i = 0; i < 4; ++i) {
      int row = i * 32 + (t >> 4);
      int sw = (c * 16) ^ ((row & 7) << 4);
      gk[i] = (const unsigned char*)(qkv + ((((size_t)b * S_ + row) * 3 + 1) * H_ + h) * D_) + sw;
      gv[i] = (const unsigned char*)(vt + (((size_t)b * H_ + h) * D_ + row) * S_) + sw;
      lbs[i] = (i * 512 + wv * 64) * 16;
    }
  }

  f32x4 oacc[8][2] = {};  // out^T: d row = df*16+hi*4+r, q col = lo (per qj)
  float m_run[2] = {-__builtin_inff(), -__builtin_inff()};
  float l_run[2] = {0.f, 0.f};
  f32x4 sacc[8][2];
  union PW { unsigned int u[4]; short8 s; };
  PW pp[2][4];       // packed P of the PREVIOUS tile (PV B-fragments)
  float coef[2];

  auto STAGE = [&](int n) {
    size_t kvK = (size_t)n * 1572864;  // 128 s-rows * 12288 B
    size_t kvV = (size_t)n * 256;      // 128 kv cols * 2 B
    unsigned char* vd = lds + 32768 + ((n & 1) << 15);
#pragma unroll
    for (int i = 0; i < 4; ++i) {
      glds16(gk[i] + kvK, lK + lbs[i]);
      glds16(gv[i] + kvV, vd + lbs[i]);
    }
  };

  auto QK = [&]() {
#pragma unroll
    for (int kf = 0; kf < 8; ++kf) {
      int kvr = kf * 16 + lo;
      int swz = (kvr & 7) << 4;
      sacc[kf][0] = f32x4{0.f, 0.f, 0.f, 0.f};
      sacc[kf][1] = f32x4{0.f, 0.f, 0.f, 0.f};
#pragma unroll
      for (int ks = 0; ks < 4; ++ks) {
        short8 kfr = *(const short8*)(lK + kvr * 256 + ((ks * 64 + hi * 16) ^ swz));
        sacc[kf][0] = __builtin_amdgcn_mfma_f32_16x16x32_bf16(kfr, qf[0][ks], sacc[kf][0], 0, 0, 0);
        sacc[kf][1] = __builtin_amdgcn_mfma_f32_16x16x32_bf16(kfr, qf[1][ks], sacc[kf][1], 0, 0, 0);
      }
    }
  };

  // PV of the PREVIOUS tile from registers pp + V in LDS buffer vb.
  auto PV = [&](unsigned char* vb) {
#pragma unroll
    for (int ks = 0; ks < 4; ++ks) {
#pragma unroll
      for (int df = 0; df < 8; ++df) {
        int dr = df * 16 + lo;
        short8 vf = *(const short8*)(vb + dr * 256 + ((ks * 64 + hi * 16) ^ ((dr & 7) << 4)));
        oacc[df][0] = __builtin_amdgcn_mfma_f32_16x16x32_bf16(vf, pp[0][ks].s, oacc[df][0], 0, 0, 0);
        oacc[df][1] = __builtin_amdgcn_mfma_f32_16x16x32_bf16(vf, pp[1][ks].s, oacc[df][1], 0, 0, 0);
      }
    }
  };

  // softmax-compute (sacc -> p, coef, l_run) + oacc rescale. In source this
  // sits AFTER PV; rescale is ordered after PV via the oacc dependence chain,
  // while the sacc-only parts are free to interleave with PV's MFMAs.
  auto SOFTMAX = [&]() {
    float m2[2], li[2];
#pragma unroll
    for (int qj = 0; qj < 2; ++qj) {
      float mloc = -__builtin_inff();
#pragma unroll
      for (int kf = 0; kf < 8; ++kf)
#pragma unroll
        for (int r = 0; r < 4; ++r) mloc = fmaxf(mloc, sacc[kf][qj][r]);
      mloc = fmaxf(mloc, __shfl_xor(mloc, 16));
      mloc = fmaxf(mloc, __shfl_xor(mloc, 32));
      m2[qj] = mloc * c1;
      float lloc = 0.f;
#pragma unroll
      for (int kf = 0; kf < 8; ++kf)
#pragma unroll
        for (int r = 0; r < 4; ++r) {
          float p = exp2f_(fmaf(sacc[kf][qj][r], c1, -m2[qj]));
          sacc[kf][qj][r] = p;
          lloc += p;
        }
      lloc += __shfl_xor(lloc, 16);
      lloc += __shfl_xor(lloc, 32);
      li[qj] = lloc;  // = l_ij
    }
    if (__all(m2[0] <= m_run[0] && m2[1] <= m_run[1])) {
      // exact skip: m_new == m_run, alpha == 1
#pragma unroll
      for (int qj = 0; qj < 2; ++qj) {
        coef[qj] = exp2f_(m2[qj] - m_run[qj]) * li[qj];
        l_run[qj] += coef[qj];
      }
    } else {
      float alpha[2];
#pragma unroll
      for (int qj = 0; qj < 2; ++qj) {
        float mn = fmaxf(m_run[qj], m2[qj]);
        alpha[qj] = exp2f_(m_run[qj] - mn);
        coef[qj] = exp2f_(m2[qj] - mn) * li[qj];
        l_run[qj] = alpha[qj] * l_run[qj] + coef[qj];
        m_run[qj] = mn;
      }
#pragma unroll
      for (int df = 0; df < 8; ++df)
#pragma unroll
        for (int qj = 0; qj < 2; ++qj)
#pragma unroll
          for (int r = 0; r < 4; ++r) oacc[df][qj][r] *= alpha[qj];
    }
  };

  // P -> PV B-fragments entirely in-register (R3 mapping, HW-verified).
  auto PACK = [&]() {
#pragma unroll
    for (int qj = 0; qj < 2; ++qj) {
      float cf = coef[qj];
      unsigned int Wp[8][2];
#pragma unroll
      for (int kf = 0; kf < 8; ++kf) {
        Wp[kf][0] = cvt_pk_bf16(sacc[kf][qj][0] * cf, sacc[kf][qj][1] * cf);
        Wp[kf][1] = cvt_pk_bf16(sacc[kf][qj][2] * cf, sacc[kf][qj][3] * cf);
      }
#pragma unroll
      for (int ks = 0; ks < 4; ++ks) {
        unsigned int a0 = Wp[2 * ks][0], b0 = Wp[2 * ks + 1][0];
        unsigned int a1 = Wp[2 * ks][1], b1 = Wp[2 * ks + 1][1];
        asm("v_permlane32_swap_b32 %0, %1" : "+v"(a0), "+v"(b0));
        asm("v_permlane16_swap_b32 %0, %1" : "+v"(a0), "+v"(b0));
        asm("v_permlane32_swap_b32 %0, %1" : "+v"(a1), "+v"(b1));
        asm("v_permlane16_swap_b32 %0, %1" : "+v"(a1), "+v"(b1));
        pp[qj][ks].u[0] = a0;
        pp[qj][ks].u[1] = a1;
        pp[qj][ks].u[2] = b0;
        pp[qj][ks].u[3] = b1;
      }
    }
  };

  // ---- pipeline ----
  STAGE(0);
  // iter 0 (peeled: no PV yet)
  asm volatile("s_waitcnt vmcnt(0)" ::: "memory");
  asm volatile("s_barrier" ::: "memory");
  QK();
  SOFTMAX();
  asm volatile("s_barrier" ::: "memory");
  STAGE(1);
  PACK();

  for (int jb = 1; jb < 32; ++jb) {
    asm volatile("s_waitcnt vmcnt(0)" ::: "memory");
    asm volatile("s_barrier" ::: "memory");  // tile jb K/V visible block-wide
    QK();
    PV(lds + 32768 + (((jb & 1) ^ 1) << 15));  // PV(jb-1), V from vbuf[(jb-1)&1]
    SOFTMAX();
    // all waves done reading K(jb) [QK MFMAs consumed] and V(jb-1) [PV MFMAs
    // consumed] before restage overwrites them.
    asm volatile("s_barrier" ::: "memory");
    if (jb < 31) STAGE(jb + 1);
    PACK();
  }
  PV(lds + 65536);  // final tile 31, V from vbuf[1]

  // epilogue: out[q][d] = oacc^T / l_run, transpose via lds[0..64K), store
#pragma unroll
  for (int qj = 0; qj < 2; ++qj) {
    int rq = wv * 32 + qj * 16 + lo;
    int swzq = (rq & 7) << 4;
    float inv = 1.0f / l_run[qj];
#pragma unroll
    for (int df = 0; df < 8; ++df) {
      uint2 pk;
      pk.x = cvt_pk_bf16(oacc[df][qj][0] * inv, oacc[df][qj][1] * inv);
      pk.y = cvt_pk_bf16(oacc[df][qj][2] * inv, oacc[df][qj][3] * inv);
      *(uint2*)(lds + rq * 256 + ((df * 32 + hi * 8) ^ swzq)) = pk;
    }
  }
  __syncthreads();
#pragma unroll
  for (int i = 0; i < 8; ++i) {
    int row = i * 32 + (t >> 4);
    int c = t & 15;
    uint4 val = *(const uint4*)(lds + row * 256 + ((c * 16) ^ ((row & 7) << 4)));
    unsigned short* dst = abuf + (((size_t)b * S_ + q0 + row) * H_ + h) * D_ + c * 8;
    *(uint4*)dst = val;
  }
}

extern "C" void kernel_launch(void* const* d_in, const int* in_sizes, int n_in,
                              void* d_out, int out_size, void* d_ws, size_t ws_size,
                              hipStream_t stream) {
  const float* x = (const float*)d_in[0];
  const float* w_qkv = (const float*)d_in[1];
  const float* w_out = (const float*)d_in[2];
  const float* b_out = (const float*)d_in[3];
  float* out = (float*)d_out;
  char* ws = (char*)d_ws;

  unsigned short* xb    = (unsigned short*)(ws);
  unsigned short* wqkvb = (unsigned short*)(ws + 33554432);
  unsigned short* woutb = (unsigned short*)(ws + 58720256);
  unsigned short* qkvb  = (unsigned short*)(ws + 67108864);
  unsigned short* vtb   = (unsigned short*)(ws + 167772160);
  unsigned short* abuf  = xb;  // x dead after gemm1; reuse

  cvtk<<<2048, 256, 0, stream>>>(x, xb, (B_ * S_ * E_) / 4);
  cvtk<<<2048, 256, 0, stream>>>(w_qkv, wqkvb, (3 * E_ * E_) / 4);
  cvtk<<<1024, 256, 0, stream>>>(w_out, woutb, (E_ * E_) / 4);

  gemm_nt<0><<<64 * 48, 256, 0, stream>>>(xb, wqkvb, (void*)qkvb, nullptr,
                                          B_ * S_, 3 * E_, E_, 48);
  transpose_v<<<1024, 256, 0, stream>>>(qkvb, vtb);
  attn_fwd<<<512, 512, 0, stream>>>(qkvb, vtb, abuf);
  gemm_nt<1><<<64 * 16, 256, 0, stream>>>(abuf, woutb, (void*)out, b_out,
                                          B_ * S_, E_, E_, 16);
}

// Round 8
// 755.944 us; speedup vs baseline: 1.1488x; 1.1488x over previous
//
#include <hip/hip_runtime.h>
#include <hip/hip_bf16.h>
#include <stdint.h>

#define DEV __device__ __forceinline__

typedef __attribute__((ext_vector_type(8))) short short8;
typedef __attribute__((ext_vector_type(4))) float f32x4;

#define B_ 2
#define S_ 4096
#define E_ 2048
#define H_ 16
#define D_ 128

DEV unsigned short f2bf(float x) {
  union { float f; uint32_t u; } a; a.f = x;
  uint32_t r = a.u + 0x7fffu + ((a.u >> 16) & 1u);
  return (unsigned short)(r >> 16);
}

DEV unsigned int cvt_pk_bf16(float a, float b) {
  unsigned int r;
  asm("v_cvt_pk_bf16_f32 %0, %1, %2" : "=v"(r) : "v"(a), "v"(b));
  return r;
}

DEV float exp2f_(float x) { return __builtin_amdgcn_exp2f(x); }

DEV void glds16(const void* g, void* l) {
  __builtin_amdgcn_global_load_lds(
      (const __attribute__((address_space(1))) uint32_t*)g,
      (__attribute__((address_space(3))) uint32_t*)l, 16, 0, 0);
}

__global__ __launch_bounds__(256) void cvtk(const float* __restrict__ in,
                                            unsigned short* __restrict__ out, int n4) {
  int i = blockIdx.x * blockDim.x + threadIdx.x;
  int stride = gridDim.x * blockDim.x;
  for (; i < n4; i += stride) {
    float4 v = ((const float4*)in)[i];
    ushort4 o;
    o.x = f2bf(v.x); o.y = f2bf(v.y); o.z = f2bf(v.z); o.w = f2bf(v.w);
    ((ushort4*)out)[i] = o;
  }
}

// C = A(MxK) * B(NxK)^T ; all bf16 inputs, fp32 accumulate.
template<int OUT_F32>
__global__ __launch_bounds__(256) void gemm_nt(
    const unsigned short* __restrict__ A,
    const unsigned short* __restrict__ Bm,
    void* __restrict__ Cp,
    const float* __restrict__ bias,
    int M, int N, int K, int nbn)
{
  __shared__ __align__(16) unsigned char lA[128 * 64];
  __shared__ __align__(16) unsigned char lB[128 * 64];
  int bid = blockIdx.x;
  int bm = bid / nbn, bn = bid % nbn;
  int t = threadIdx.x;
  int lane = t & 63, wv = t >> 6;
  int hi = lane >> 4, lo = lane & 15;
  int wm = wv >> 1, wn = wv & 1;
  int m0 = bm * 128, n0 = bn * 128;

  f32x4 acc[4][4] = {};

  for (int k0 = 0; k0 < K; k0 += 32) {
#pragma unroll
    for (int i = 0; i < 2; ++i) {
      int slot = i * 256 + t;
      int row = slot >> 2, c = slot & 3;
      int lbase = (i * 256 + wv * 64) * 16;
      glds16(A + (size_t)(m0 + row) * K + k0 + c * 8, lA + lbase);
      glds16(Bm + (size_t)(n0 + row) * K + k0 + c * 8, lB + lbase);
    }
    __syncthreads();
    short8 af[4], bfr[4];
#pragma unroll
    for (int mi = 0; mi < 4; ++mi)
      af[mi] = *(const short8*)(lA + (wm * 64 + mi * 16 + lo) * 64 + hi * 16);
#pragma unroll
    for (int nj = 0; nj < 4; ++nj)
      bfr[nj] = *(const short8*)(lB + (wn * 64 + nj * 16 + lo) * 64 + hi * 16);
#pragma unroll
    for (int mi = 0; mi < 4; ++mi)
#pragma unroll
      for (int nj = 0; nj < 4; ++nj)
        acc[mi][nj] = __builtin_amdgcn_mfma_f32_16x16x32_bf16(af[mi], bfr[nj], acc[mi][nj], 0, 0, 0);
    __syncthreads();
  }

  if constexpr (OUT_F32) {
    float* C = (float*)Cp;
#pragma unroll
    for (int mi = 0; mi < 4; ++mi)
#pragma unroll
      for (int nj = 0; nj < 4; ++nj) {
        int row = m0 + wm * 64 + mi * 16 + hi * 4;
        int col = n0 + wn * 64 + nj * 16 + lo;
        float bv = bias[col];
#pragma unroll
        for (int r = 0; r < 4; ++r)
          C[(size_t)(row + r) * N + col] = acc[mi][nj][r] + bv;
      }
  } else {
    unsigned short* C = (unsigned short*)Cp;
#pragma unroll
    for (int mi = 0; mi < 4; ++mi)
#pragma unroll
      for (int nj = 0; nj < 4; ++nj) {
        int row = m0 + wm * 64 + mi * 16 + hi * 4;
        int col = n0 + wn * 64 + nj * 16 + lo;
#pragma unroll
        for (int r = 0; r < 4; ++r)
          C[(size_t)(row + r) * N + col] = f2bf(acc[mi][nj][r]);
      }
  }
}

// vt[b,h,d,s] = qkv[b,s,2,h,d]
__global__ __launch_bounds__(256) void transpose_v(const unsigned short* __restrict__ qkv,
                                                   unsigned short* __restrict__ vt) {
  __shared__ __align__(16) unsigned char tl[32768];
  int bid = blockIdx.x;
  int st = bid & 31, bh = bid >> 5;
  int h = bh & 15, b = bh >> 4;
  int s0 = st * 128;
  int t = threadIdx.x, c = t & 15, rr = t >> 4;
#pragma unroll
  for (int i = 0; i < 8; ++i) {
    int s = rr + i * 16;
    const unsigned short* g = qkv + ((((size_t)b * S_ + s0 + s) * 3 + 2) * H_ + h) * D_ + c * 8;
    *(uint4*)(tl + s * 256 + ((c * 16) ^ (((s >> 3) & 7) << 4))) = *(const uint4*)g;
  }
  __syncthreads();
#pragma unroll
  for (int i = 0; i < 8; ++i) {
    int d = rr + i * 16;
    unsigned int w[4];
#pragma unroll
    for (int jj = 0; jj < 4; ++jj) {
      int s_a = c * 8 + jj * 2;
      unsigned int u0 = *(const unsigned short*)(tl + s_a * 256 + ((d * 2) ^ ((c & 7) << 4)));
      unsigned int u1 = *(const unsigned short*)(tl + (s_a + 1) * 256 + ((d * 2) ^ ((c & 7) << 4)));
      w[jj] = u0 | (u1 << 16);
    }
    uint4 val; val.x = w[0]; val.y = w[1]; val.z = w[2]; val.w = w[3];
    unsigned short* g = vt + (((size_t)b * H_ + h) * D_ + d) * S_ + s0 + c * 8;
    *(uint4*)g = val;
  }
}

// Flash attention, reference's extra l_ij semantics, KV block = 128.
// 8 waves x 32 q rows = 256-q block. LDS: K 32K | V 32K = 64K, single-buffered.
// P NEVER touches LDS: permlane32/16_swap builds PV B-fragments in-register
// (R3 mapping, HW-verified). Register diet: 2 base pointers, no Wp array.
__global__ __launch_bounds__(512, 2) void attn_fwd(
    const unsigned short* __restrict__ qkv,  // [B,S,3,H,D] bf16
    const unsigned short* __restrict__ vt,   // [B,H,D,S] bf16
    unsigned short* __restrict__ abuf)       // [B,S,H*D] bf16
{
  __shared__ __align__(16) unsigned char lds[65536];
  unsigned char* lK = lds;
  unsigned char* lV = lds + 32768;

  // XCD-chunked swizzle: 512 blocks, 8 XCDs, 64 consecutive logical blocks per
  // XCD -> the 16 q-blocks sharing one (b,h)'s K/V land on the same XCD's L2.
  int bid = (blockIdx.x & 7) * 64 + (blockIdx.x >> 3);
  int qb = bid & 15, bh = bid >> 4;
  int h = bh & 15, b = bh >> 4;
  int t = threadIdx.x, lane = t & 63, wv = t >> 6;
  int hi = lane >> 4, lo = lane & 15;
  int q0 = qb * 256;
  const float c1 = 0.12751744f;  // (1/sqrt(128)) * log2(e)

  // Q fragments: 2 q sub-tiles (B-operand: col = q, k = d)
  short8 qf[2][4];
#pragma unroll
  for (int qj = 0; qj < 2; ++qj) {
    const unsigned short* qbase =
        qkv + ((((size_t)b * S_ + q0 + wv * 32 + qj * 16 + lo) * 3 + 0) * H_ + h) * D_;
#pragma unroll
    for (int ks = 0; ks < 4; ++ks)
      qf[qj][ks] = *(const short8*)(qbase + ks * 32 + hi * 8);
  }

  // staging bases (pre-swizzled global source, linear LDS dest).
  // thread t stages rows (i*32 + (t>>4)) for i=0..3; swizzled col from t.
  int sw = ((t & 15) * 16) ^ (((t >> 4) & 7) << 4);
  const unsigned char* gkb =
      (const unsigned char*)(qkv + (((size_t)b * S_ * 3 + 1) * H_ + h) * D_) +
      (size_t)(t >> 4) * 12288 + sw;                 // K row stride 3*H*D*2 = 12288 B
  const unsigned char* gvb =
      (const unsigned char*)(vt + ((size_t)b * H_ + h) * D_ * S_) +
      (size_t)(t >> 4) * 8192 + sw;                  // V^T row stride S*2 = 8192 B
  unsigned char* lkd = lK + wv * 1024;               // wave-uniform LDS dest base
  unsigned char* lvd = lV + wv * 1024;

  f32x4 oacc[8][2] = {};  // out^T: d row = df*16+hi*4+r, q col = lo (per qj)
  float m_run[2] = {-__builtin_inff(), -__builtin_inff()};
  float l_run[2] = {0.f, 0.f};
  union PW { unsigned int u[4]; short8 s; };
  PW pp[2][4];  // packed P as PV B-fragments (in-register)

  // prologue: stage tile 0
#pragma unroll
  for (int i = 0; i < 4; ++i) {
    glds16(gkb + i * 393216, lkd + i * 8192);   // 32 K rows * 12288 B
    glds16(gvb + i * 262144, lvd + i * 8192);   // 32 V rows * 8192 B
  }

  for (int jb = 0; jb < 32; ++jb) {
    asm volatile("s_waitcnt vmcnt(0)" ::: "memory");
    asm volatile("s_barrier" ::: "memory");  // tile jb visible block-wide

    // S^T = K · Q^T
    f32x4 sacc[8][2];
    __builtin_amdgcn_s_setprio(1);
#pragma unroll
    for (int kf = 0; kf < 8; ++kf) {
      int kvr = kf * 16 + lo;
      int swz = (kvr & 7) << 4;
      sacc[kf][0] = f32x4{0.f, 0.f, 0.f, 0.f};
      sacc[kf][1] = f32x4{0.f, 0.f, 0.f, 0.f};
#pragma unroll
      for (int ks = 0; ks < 4; ++ks) {
        short8 kfr = *(const short8*)(lK + kvr * 256 + ((ks * 64 + hi * 16) ^ swz));
        sacc[kf][0] = __builtin_amdgcn_mfma_f32_16x16x32_bf16(kfr, qf[0][ks], sacc[kf][0], 0, 0, 0);
        sacc[kf][1] = __builtin_amdgcn_mfma_f32_16x16x32_bf16(kfr, qf[1][ks], sacc[kf][1], 0, 0, 0);
      }
    }
    __builtin_amdgcn_s_setprio(0);

    // block softmax in log2 domain (per-lane q col = lo; hi replicas hold kv quarters)
    float m2[2], li[2], coef[2];
#pragma unroll
    for (int qj = 0; qj < 2; ++qj) {
      float mloc = -__builtin_inff();
#pragma unroll
      for (int kf = 0; kf < 8; ++kf)
#pragma unroll
        for (int r = 0; r < 4; ++r) mloc = fmaxf(mloc, sacc[kf][qj][r]);
      mloc = fmaxf(mloc, __shfl_xor(mloc, 16));
      mloc = fmaxf(mloc, __shfl_xor(mloc, 32));
      m2[qj] = mloc * c1;
      float lloc = 0.f;
#pragma unroll
      for (int kf = 0; kf < 8; ++kf)
#pragma unroll
        for (int r = 0; r < 4; ++r) {
          float p = exp2f_(fmaf(sacc[kf][qj][r], c1, -m2[qj]));
          sacc[kf][qj][r] = p;
          lloc += p;
        }
      lloc += __shfl_xor(lloc, 16);
      lloc += __shfl_xor(lloc, 32);
      li[qj] = lloc;  // = l_ij
    }

    if (__all(m2[0] <= m_run[0] && m2[1] <= m_run[1])) {
      // exact skip: m_new == m_run, alpha == 1
#pragma unroll
      for (int qj = 0; qj < 2; ++qj) {
        coef[qj] = exp2f_(m2[qj] - m_run[qj]) * li[qj];
        l_run[qj] += coef[qj];
      }
    } else {
      float alpha[2];
#pragma unroll
      for (int qj = 0; qj < 2; ++qj) {
        float mn = fmaxf(m_run[qj], m2[qj]);
        alpha[qj] = exp2f_(m_run[qj] - mn);
        coef[qj] = exp2f_(m2[qj] - mn) * li[qj];
        l_run[qj] = alpha[qj] * l_run[qj] + coef[qj];
        m_run[qj] = mn;
      }
#pragma unroll
      for (int df = 0; df < 8; ++df)
#pragma unroll
        for (int qj = 0; qj < 2; ++qj)
#pragma unroll
          for (int r = 0; r < 4; ++r) oacc[df][qj][r] *= alpha[qj];
    }

    // PACK: P -> PV B-fragments in-register (R3 mapping). Per (qj, ks): only
    // 4 u32 temporaries live; sacc dies as pp is built.
#pragma unroll
    for (int qj = 0; qj < 2; ++qj) {
      float cf = coef[qj];
#pragma unroll
      for (int ks = 0; ks < 4; ++ks) {
        unsigned int a0 = cvt_pk_bf16(sacc[2 * ks][qj][0] * cf, sacc[2 * ks][qj][1] * cf);
        unsigned int b0 = cvt_pk_bf16(sacc[2 * ks + 1][qj][0] * cf, sacc[2 * ks + 1][qj][1] * cf);
        unsigned int a1 = cvt_pk_bf16(sacc[2 * ks][qj][2] * cf, sacc[2 * ks][qj][3] * cf);
        unsigned int b1 = cvt_pk_bf16(sacc[2 * ks + 1][qj][2] * cf, sacc[2 * ks + 1][qj][3] * cf);
        asm("v_permlane32_swap_b32 %0, %1" : "+v"(a0), "+v"(b0));
        asm("v_permlane16_swap_b32 %0, %1" : "+v"(a0), "+v"(b0));
        asm("v_permlane32_swap_b32 %0, %1" : "+v"(a1), "+v"(b1));
        asm("v_permlane16_swap_b32 %0, %1" : "+v"(a1), "+v"(b1));
        pp[qj][ks].u[0] = a0;
        pp[qj][ks].u[1] = a1;
        pp[qj][ks].u[2] = b0;
        pp[qj][ks].u[3] = b1;
      }
    }

    // PV: out^T += Vt · P^T (P from registers; each V fragment feeds 2 MFMAs)
    __builtin_amdgcn_s_setprio(1);
#pragma unroll
    for (int ks = 0; ks < 4; ++ks) {
#pragma unroll
      for (int df = 0; df < 8; ++df) {
        int dr = df * 16 + lo;
        short8 vf = *(const short8*)(lV + dr * 256 + ((ks * 64 + hi * 16) ^ ((dr & 7) << 4)));
        oacc[df][0] = __builtin_amdgcn_mfma_f32_16x16x32_bf16(vf, pp[0][ks].s, oacc[df][0], 0, 0, 0);
        oacc[df][1] = __builtin_amdgcn_mfma_f32_16x16x32_bf16(vf, pp[1][ks].s, oacc[df][1], 0, 0, 0);
      }
    }
    __builtin_amdgcn_s_setprio(0);

    // all waves done reading K/V before restage overwrites them.
    asm volatile("s_barrier" ::: "memory");
    if (jb < 31) {
      size_t kvK = (size_t)(jb + 1) * 1572864;  // 128 s-rows * 12288 B
      size_t kvV = (size_t)(jb + 1) * 256;      // 128 kv cols * 2 B
#pragma unroll
      for (int i = 0; i < 4; ++i) {
        glds16(gkb + kvK + i * 393216, lkd + i * 8192);
        glds16(gvb + kvV + i * 262144, lvd + i * 8192);
      }
    }
  }

  // epilogue: out[q][d] = oacc^T / l_run, transpose via lds (64K), coalesced store
  asm volatile("s_barrier" ::: "memory");  // last-iter readers done (paranoia; cheap)
#pragma unroll
  for (int qj = 0; qj < 2; ++qj) {
    int rq = wv * 32 + qj * 16 + lo;
    int swzq = (rq & 7) << 4;
    float inv = 1.0f / l_run[qj];
#pragma unroll
    for (int df = 0; df < 8; ++df) {
      uint2 pk;
      pk.x = cvt_pk_bf16(oacc[df][qj][0] * inv, oacc[df][qj][1] * inv);
      pk.y = cvt_pk_bf16(oacc[df][qj][2] * inv, oacc[df][qj][3] * inv);
      *(uint2*)(lds + rq * 256 + ((df * 32 + hi * 8) ^ swzq)) = pk;
    }
  }
  __syncthreads();
#pragma unroll
  for (int i = 0; i < 8; ++i) {
    int row = i * 32 + (t >> 4);
    int c = t & 15;
    uint4 val = *(const uint4*)(lds + row * 256 + ((c * 16) ^ ((row & 7) << 4)));
    unsigned short* dst = abuf + (((size_t)b * S_ + q0 + row) * H_ + h) * D_ + c * 8;
    *(uint4*)dst = val;
  }
}

extern "C" void kernel_launch(void* const* d_in, const int* in_sizes, int n_in,
                              void* d_out, int out_size, void* d_ws, size_t ws_size,
                              hipStream_t stream) {
  const float* x = (const float*)d_in[0];
  const float* w_qkv = (const float*)d_in[1];
  const float* w_out = (const float*)d_in[2];
  const float* b_out = (const float*)d_in[3];
  float* out = (float*)d_out;
  char* ws = (char*)d_ws;

  unsigned short* xb    = (unsigned short*)(ws);
  unsigned short* wqkvb = (unsigned short*)(ws + 33554432);
  unsigned short* woutb = (unsigned short*)(ws + 58720256);
  unsigned short* qkvb  = (unsigned short*)(ws + 67108864);
  unsigned short* vtb   = (unsigned short*)(ws + 167772160);
  unsigned short* abuf  = xb;  // x dead after gemm1; reuse

  cvtk<<<2048, 256, 0, stream>>>(x, xb, (B_ * S_ * E_) / 4);
  cvtk<<<2048, 256, 0, stream>>>(w_qkv, wqkvb, (3 * E_ * E_) / 4);
  cvtk<<<1024, 256, 0, stream>>>(w_out, woutb, (E_ * E_) / 4);

  gemm_nt<0><<<64 * 48, 256, 0, stream>>>(xb, wqkvb, (void*)qkvb, nullptr,
                                          B_ * S_, 3 * E_, E_, 48);
  transpose_v<<<1024, 256, 0, stream>>>(qkvb, vtb);
  attn_fwd<<<512, 512, 0, stream>>>(qkvb, vtb, abuf);
  gemm_nt<1><<<64 * 16, 256, 0, stream>>>(abuf, woutb, (void*)out, b_out,
                                          B_ * S_, E_, E_, 16);
}

// Round 9
// 637.598 us; speedup vs baseline: 1.3621x; 1.1856x over previous
//
#include <hip/hip_runtime.h>
#include <hip/hip_bf16.h>
#include <stdint.h>

#define DEV __device__ __forceinline__

typedef __attribute__((ext_vector_type(8))) short short8;
typedef __attribute__((ext_vector_type(4))) float f32x4;

#define B_ 2
#define S_ 4096
#define E_ 2048
#define H_ 16
#define D_ 128

#define BAR() asm volatile("s_barrier" ::: "memory")
#define LGKM0() asm volatile("s_waitcnt lgkmcnt(0)" ::: "memory")
#define VMC(N) asm volatile("s_waitcnt vmcnt(" #N ")" ::: "memory")

DEV unsigned short f2bf(float x) {
  union { float f; uint32_t u; } a; a.f = x;
  uint32_t r = a.u + 0x7fffu + ((a.u >> 16) & 1u);
  return (unsigned short)(r >> 16);
}

DEV unsigned int cvt_pk_bf16(float a, float b) {
  unsigned int r;
  asm("v_cvt_pk_bf16_f32 %0, %1, %2" : "=v"(r) : "v"(a), "v"(b));
  return r;
}

DEV float exp2f_(float x) { return __builtin_amdgcn_exp2f(x); }

DEV void glds16(const void* g, void* l) {
  __builtin_amdgcn_global_load_lds(
      (const __attribute__((address_space(1))) uint32_t*)g,
      (__attribute__((address_space(3))) uint32_t*)l, 16, 0, 0);
}

__global__ __launch_bounds__(256) void cvtk(const float* __restrict__ in,
                                            unsigned short* __restrict__ out, int n4) {
  int i = blockIdx.x * blockDim.x + threadIdx.x;
  int stride = gridDim.x * blockDim.x;
  for (; i < n4; i += stride) {
    float4 v = ((const float4*)in)[i];
    ushort4 o;
    o.x = f2bf(v.x); o.y = f2bf(v.y); o.z = f2bf(v.z); o.w = f2bf(v.w);
    ((ushort4*)out)[i] = o;
  }
}

// C = A(MxK) * B(NxK)^T, 256x256 tile, BK=64, 8-phase schedule with counted
// vmcnt (T2+T3+T4+T5 per m201). 8 waves (2M x 4N), per-wave C = 128x64.
// LDS 128K: buf d in {0,1}: A at d*64K (2 halves of 16K), B at d*64K+32K.
// Swizzle: byte col ^ ((row&7)<<4), applied via pre-swizzled global source.
template<int OUT_F32>
__global__ __launch_bounds__(512, 2) void gemm256(
    const unsigned short* __restrict__ A,
    const unsigned short* __restrict__ Bm,
    void* __restrict__ Cp,
    const float* __restrict__ bias,
    int M, int N, int K, int nbn)
{
  __shared__ __align__(16) unsigned char lds[131072];
  const int NT = K >> 6;   // K-tiles of 64 (even)
  const int K2 = K * 2;    // row stride bytes
  int cpx = gridDim.x >> 3;
  int bid = (blockIdx.x & 7) * cpx + (blockIdx.x >> 3);  // XCD-chunked
  int bm = bid / nbn, bn = bid % nbn;
  int m0 = bm * 256, n0 = bn * 256;
  int t = threadIdx.x, lane = t & 63, wv = t >> 6;
  int lo = lane & 15, hi = lane >> 4;
  int wm = wv >> 2, wn = wv & 3;

  // stage sources: thread covers row (t>>3)+{0,64} of a 128-row half, 16B
  // chunk (t&7); global col pre-swizzled so linear LDS + swizzled read match.
  int colsw = ((t & 7) * 16) ^ (((t >> 3) & 7) << 4);
  const unsigned char* gA = (const unsigned char*)A + (size_t)(m0 + (t >> 3)) * K2 + colsw;
  const unsigned char* gB = (const unsigned char*)Bm + (size_t)(n0 + (t >> 3)) * K2 + colsw;

  // ds_read bases (A rows: wm*128 + mf*16 + lo; B rows: wn*64 + nf*16 + lo)
  int swzl = (lo & 7) << 4;
  int colk0 = (hi * 16) ^ swzl;          // ks=0 col bytes, swizzled
  int colk1 = (64 + hi * 16) ^ swzl;     // ks=1
  unsigned char* rdA = lds + wm * 16384 + lo * 128;
  unsigned char* rdB = lds + 32768 + (wn >> 1) * 16384 + ((wn & 1) * 64 + lo) * 128;

  f32x4 acc[8][4] = {};

  auto STG = [&](int isA, int d, int h, int kt) {
    if (kt >= NT) return;
    const unsigned char* g = (isA ? gA : gB) + (size_t)h * 128 * K2 + (size_t)kt * 128;
    unsigned char* l = lds + (isA ? 0 : 32768) + d * 65536 + h * 16384 + wv * 1024;
    glds16(g, l);
    glds16(g + (size_t)64 * K2, l + 8192);
  };
  auto DSA = [&](int d, int g4, int colk, short8* dst) {
#pragma unroll
    for (int i = 0; i < 4; ++i)
      dst[i] = *(const short8*)(rdA + d * 65536 + (g4 * 4 + i) * 2048 + colk);
  };
  auto DSB = [&](int d, int colk, short8* dst) {
#pragma unroll
    for (int i = 0; i < 4; ++i)
      dst[i] = *(const short8*)(rdB + d * 65536 + i * 2048 + colk);
  };
  auto MM = [&](int g4, short8* a, short8* b) {
    __builtin_amdgcn_s_setprio(1);
#pragma unroll
    for (int i = 0; i < 4; ++i)
#pragma unroll
      for (int j = 0; j < 4; ++j)
        acc[g4 * 4 + i][j] =
            __builtin_amdgcn_mfma_f32_16x16x32_bf16(a[i], b[j], acc[g4 * 4 + i][j], 0, 0, 0);
    __builtin_amdgcn_s_setprio(0);
  };

  // prologue: tile0 -> buf0 (A0,A1,B0,B1), B halves of tile1 -> buf1
  STG(1, 0, 0, 0); STG(1, 0, 1, 0); STG(0, 0, 0, 0); STG(0, 0, 1, 0);
  STG(0, 1, 0, 1); STG(0, 1, 1, 1);
  VMC(4);  // tile0's 8 loads done (tile1-B 4 still in flight)
  BAR();

  short8 aT[4], aU[4], b0[4], b1[4];
  const int TL = (NT >> 1) - 1;
  for (int it = 0; it <= TL; ++it) {
    int j0 = 2 * it;
    // ---- phases 0-3: compute tile j0 (buf0) ----
    DSA(0, 0, colk0, aT); DSB(0, colk0, b0);
    STG(1, 1, 0, j0 + 1);                       // A0(2t+1) -> buf1
    BAR(); MM(0, aT, b0); LGKM0(); BAR();
    DSA(0, 1, colk0, aU); DSB(0, colk1, b1);
    STG(1, 1, 1, j0 + 1);                       // A1(2t+1) -> buf1
    BAR(); MM(1, aU, b0); LGKM0(); BAR();
    DSA(0, 0, colk1, aT);
    STG(0, 0, 0, j0 + 2);                       // B0(2t+2) -> buf0
    BAR(); MM(0, aT, b1); LGKM0(); BAR();
    DSA(0, 1, colk1, aU);
    STG(0, 0, 1, j0 + 2);                       // B1(2t+2) -> buf0
    BAR(); MM(1, aU, b1); LGKM0();
    if (it == TL) { VMC(0); } else { VMC(4); }  // tile 2t+1 fully landed
    BAR();
    // ---- phases 4-7: compute tile j0+1 (buf1) ----
    DSA(1, 0, colk0, aT); DSB(1, colk0, b0);
    STG(1, 0, 0, j0 + 2);                       // A0(2t+2) -> buf0
    BAR(); MM(0, aT, b0); LGKM0(); BAR();
    DSA(1, 1, colk0, aU); DSB(1, colk1, b1);
    STG(1, 0, 1, j0 + 2);                       // A1(2t+2) -> buf0
    BAR(); MM(1, aU, b0); LGKM0(); BAR();
    DSA(1, 0, colk1, aT);
    STG(0, 1, 0, j0 + 3);                       // B0(2t+3) -> buf1
    BAR(); MM(0, aT, b1); LGKM0(); BAR();
    DSA(1, 1, colk1, aU);
    STG(0, 1, 1, j0 + 3);                       // B1(2t+3) -> buf1
    BAR(); MM(1, aU, b1); LGKM0(); VMC(4);      // tile 2t+2 fully landed
    BAR();
  }

  // epilogue
  if constexpr (OUT_F32) {
    float* C = (float*)Cp;
#pragma unroll
    for (int mf = 0; mf < 8; ++mf)
#pragma unroll
      for (int nf = 0; nf < 4; ++nf) {
        int row = m0 + wm * 128 + mf * 16 + hi * 4;
        int col = n0 + wn * 64 + nf * 16 + lo;
        float bv = bias[col];
#pragma unroll
        for (int r = 0; r < 4; ++r)
          C[(size_t)(row + r) * N + col] = acc[mf][nf][r] + bv;
      }
  } else {
    unsigned short* C = (unsigned short*)Cp;
#pragma unroll
    for (int mf = 0; mf < 8; ++mf)
#pragma unroll
      for (int nf = 0; nf < 4; ++nf) {
        int row = m0 + wm * 128 + mf * 16 + hi * 4;
        int col = n0 + wn * 64 + nf * 16 + lo;
#pragma unroll
        for (int r = 0; r < 4; ++r)
          C[(size_t)(row + r) * N + col] = f2bf(acc[mf][nf][r]);
      }
  }
}

// vt[b,h,d,s] = qkv[b,s,2,h,d]
__global__ __launch_bounds__(256) void transpose_v(const unsigned short* __restrict__ qkv,
                                                   unsigned short* __restrict__ vt) {
  __shared__ __align__(16) unsigned char tl[32768];
  int bid = blockIdx.x;
  int st = bid & 31, bh = bid >> 5;
  int h = bh & 15, b = bh >> 4;
  int s0 = st * 128;
  int t = threadIdx.x, c = t & 15, rr = t >> 4;
#pragma unroll
  for (int i = 0; i < 8; ++i) {
    int s = rr + i * 16;
    const unsigned short* g = qkv + ((((size_t)b * S_ + s0 + s) * 3 + 2) * H_ + h) * D_ + c * 8;
    *(uint4*)(tl + s * 256 + ((c * 16) ^ (((s >> 3) & 7) << 4))) = *(const uint4*)g;
  }
  __syncthreads();
#pragma unroll
  for (int i = 0; i < 8; ++i) {
    int d = rr + i * 16;
    unsigned int w[4];
#pragma unroll
    for (int jj = 0; jj < 4; ++jj) {
      int s_a = c * 8 + jj * 2;
      unsigned int u0 = *(const unsigned short*)(tl + s_a * 256 + ((d * 2) ^ ((c & 7) << 4)));
      unsigned int u1 = *(const unsigned short*)(tl + (s_a + 1) * 256 + ((d * 2) ^ ((c & 7) << 4)));
      w[jj] = u0 | (u1 << 16);
    }
    uint4 val; val.x = w[0]; val.y = w[1]; val.z = w[2]; val.w = w[3];
    unsigned short* g = vt + (((size_t)b * H_ + h) * D_ + d) * S_ + s0 + c * 8;
    *(uint4*)g = val;
  }
}

// Flash attention, reference's extra l_ij semantics, KV block = 128.
// 8 waves x 32 q rows = 256-q block. LDS: K 32K | V 32K = 64K, single-buffered.
// P NEVER touches LDS: permlane32/16_swap builds PV B-fragments in-register.
__global__ __launch_bounds__(512, 2) void attn_fwd(
    const unsigned short* __restrict__ qkv,  // [B,S,3,H,D] bf16
    const unsigned short* __restrict__ vt,   // [B,H,D,S] bf16
    unsigned short* __restrict__ abuf)       // [B,S,H*D] bf16
{
  __shared__ __align__(16) unsigned char lds[65536];
  unsigned char* lK = lds;
  unsigned char* lV = lds + 32768;

  int bid = (blockIdx.x & 7) * 64 + (blockIdx.x >> 3);
  int qb = bid & 15, bh = bid >> 4;
  int h = bh & 15, b = bh >> 4;
  int t = threadIdx.x, lane = t & 63, wv = t >> 6;
  int hi = lane >> 4, lo = lane & 15;
  int q0 = qb * 256;
  const float c1 = 0.12751744f;  // (1/sqrt(128)) * log2(e)

  short8 qf[2][4];
#pragma unroll
  for (int qj = 0; qj < 2; ++qj) {
    const unsigned short* qbase =
        qkv + ((((size_t)b * S_ + q0 + wv * 32 + qj * 16 + lo) * 3 + 0) * H_ + h) * D_;
#pragma unroll
    for (int ks = 0; ks < 4; ++ks)
      qf[qj][ks] = *(const short8*)(qbase + ks * 32 + hi * 8);
  }

  int sw = ((t & 15) * 16) ^ (((t >> 4) & 7) << 4);
  const unsigned char* gkb =
      (const unsigned char*)(qkv + (((size_t)b * S_ * 3 + 1) * H_ + h) * D_) +
      (size_t)(t >> 4) * 12288 + sw;
  const unsigned char* gvb =
      (const unsigned char*)(vt + ((size_t)b * H_ + h) * D_ * S_) +
      (size_t)(t >> 4) * 8192 + sw;
  unsigned char* lkd = lK + wv * 1024;
  unsigned char* lvd = lV + wv * 1024;

  f32x4 oacc[8][2] = {};
  float m_run[2] = {-__builtin_inff(), -__builtin_inff()};
  float l_run[2] = {0.f, 0.f};
  union PW { unsigned int u[4]; short8 s; };
  PW pp[2][4];

#pragma unroll
  for (int i = 0; i < 4; ++i) {
    glds16(gkb + i * 393216, lkd + i * 8192);
    glds16(gvb + i * 262144, lvd + i * 8192);
  }

  for (int jb = 0; jb < 32; ++jb) {
    VMC(0);
    BAR();

    f32x4 sacc[8][2];
    __builtin_amdgcn_s_setprio(1);
#pragma unroll
    for (int kf = 0; kf < 8; ++kf) {
      int kvr = kf * 16 + lo;
      int swz = (kvr & 7) << 4;
      sacc[kf][0] = f32x4{0.f, 0.f, 0.f, 0.f};
      sacc[kf][1] = f32x4{0.f, 0.f, 0.f, 0.f};
#pragma unroll
      for (int ks = 0; ks < 4; ++ks) {
        short8 kfr = *(const short8*)(lK + kvr * 256 + ((ks * 64 + hi * 16) ^ swz));
        sacc[kf][0] = __builtin_amdgcn_mfma_f32_16x16x32_bf16(kfr, qf[0][ks], sacc[kf][0], 0, 0, 0);
        sacc[kf][1] = __builtin_amdgcn_mfma_f32_16x16x32_bf16(kfr, qf[1][ks], sacc[kf][1], 0, 0, 0);
      }
    }
    __builtin_amdgcn_s_setprio(0);

    float m2[2], li[2], coef[2];
#pragma unroll
    for (int qj = 0; qj < 2; ++qj) {
      float mloc = -__builtin_inff();
#pragma unroll
      for (int kf = 0; kf < 8; ++kf)
#pragma unroll
        for (int r = 0; r < 4; ++r) mloc = fmaxf(mloc, sacc[kf][qj][r]);
      mloc = fmaxf(mloc, __shfl_xor(mloc, 16));
      mloc = fmaxf(mloc, __shfl_xor(mloc, 32));
      m2[qj] = mloc * c1;
      float lloc = 0.f;
#pragma unroll
      for (int kf = 0; kf < 8; ++kf)
#pragma unroll
        for (int r = 0; r < 4; ++r) {
          float p = exp2f_(fmaf(sacc[kf][qj][r], c1, -m2[qj]));
          sacc[kf][qj][r] = p;
          lloc += p;
        }
      lloc += __shfl_xor(lloc, 16);
      lloc += __shfl_xor(lloc, 32);
      li[qj] = lloc;
    }

    if (__all(m2[0] <= m_run[0] && m2[1] <= m_run[1])) {
#pragma unroll
      for (int qj = 0; qj < 2; ++qj) {
        coef[qj] = exp2f_(m2[qj] - m_run[qj]) * li[qj];
        l_run[qj] += coef[qj];
      }
    } else {
      float alpha[2];
#pragma unroll
      for (int qj = 0; qj < 2; ++qj) {
        float mn = fmaxf(m_run[qj], m2[qj]);
        alpha[qj] = exp2f_(m_run[qj] - mn);
        coef[qj] = exp2f_(m2[qj] - mn) * li[qj];
        l_run[qj] = alpha[qj] * l_run[qj] + coef[qj];
        m_run[qj] = mn;
      }
#pragma unroll
      for (int df = 0; df < 8; ++df)
#pragma unroll
        for (int qj = 0; qj < 2; ++qj)
#pragma unroll
          for (int r = 0; r < 4; ++r) oacc[df][qj][r] *= alpha[qj];
    }

#pragma unroll
    for (int qj = 0; qj < 2; ++qj) {
      float cf = coef[qj];
#pragma unroll
      for (int ks = 0; ks < 4; ++ks) {
        unsigned int a0 = cvt_pk_bf16(sacc[2 * ks][qj][0] * cf, sacc[2 * ks][qj][1] * cf);
        unsigned int b0 = cvt_pk_bf16(sacc[2 * ks + 1][qj][0] * cf, sacc[2 * ks + 1][qj][1] * cf);
        unsigned int a1 = cvt_pk_bf16(sacc[2 * ks][qj][2] * cf, sacc[2 * ks][qj][3] * cf);
        unsigned int b1 = cvt_pk_bf16(sacc[2 * ks + 1][qj][2] * cf, sacc[2 * ks + 1][qj][3] * cf);
        asm("v_permlane32_swap_b32 %0, %1" : "+v"(a0), "+v"(b0));
        asm("v_permlane16_swap_b32 %0, %1" : "+v"(a0), "+v"(b0));
        asm("v_permlane32_swap_b32 %0, %1" : "+v"(a1), "+v"(b1));
        asm("v_permlane16_swap_b32 %0, %1" : "+v"(a1), "+v"(b1));
        pp[qj][ks].u[0] = a0;
        pp[qj][ks].u[1] = a1;
        pp[qj][ks].u[2] = b0;
        pp[qj][ks].u[3] = b1;
      }
    }

    __builtin_amdgcn_s_setprio(1);
#pragma unroll
    for (int ks = 0; ks < 4; ++ks) {
#pragma unroll
      for (int df = 0; df < 8; ++df) {
        int dr = df * 16 + lo;
        short8 vf = *(const short8*)(lV + dr * 256 + ((ks * 64 + hi * 16) ^ ((dr & 7) << 4)));
        oacc[df][0] = __builtin_amdgcn_mfma_f32_16x16x32_bf16(vf, pp[0][ks].s, oacc[df][0], 0, 0, 0);
        oacc[df][1] = __builtin_amdgcn_mfma_f32_16x16x32_bf16(vf, pp[1][ks].s, oacc[df][1], 0, 0, 0);
      }
    }
    __builtin_amdgcn_s_setprio(0);

    BAR();
    if (jb < 31) {
      size_t kvK = (size_t)(jb + 1) * 1572864;
      size_t kvV = (size_t)(jb + 1) * 256;
#pragma unroll
      for (int i = 0; i < 4; ++i) {
        glds16(gkb + kvK + i * 393216, lkd + i * 8192);
        glds16(gvb + kvV + i * 262144, lvd + i * 8192);
      }
    }
  }

  BAR();
#pragma unroll
  for (int qj = 0; qj < 2; ++qj) {
    int rq = wv * 32 + qj * 16 + lo;
    int swzq = (rq & 7) << 4;
    float inv = 1.0f / l_run[qj];
#pragma unroll
    for (int df = 0; df < 8; ++df) {
      uint2 pk;
      pk.x = cvt_pk_bf16(oacc[df][qj][0] * inv, oacc[df][qj][1] * inv);
      pk.y = cvt_pk_bf16(oacc[df][qj][2] * inv, oacc[df][qj][3] * inv);
      *(uint2*)(lds + rq * 256 + ((df * 32 + hi * 8) ^ swzq)) = pk;
    }
  }
  __syncthreads();
#pragma unroll
  for (int i = 0; i < 8; ++i) {
    int row = i * 32 + (t >> 4);
    int c = t & 15;
    uint4 val = *(const uint4*)(lds + row * 256 + ((c * 16) ^ ((row & 7) << 4)));
    unsigned short* dst = abuf + (((size_t)b * S_ + q0 + row) * H_ + h) * D_ + c * 8;
    *(uint4*)dst = val;
  }
}

extern "C" void kernel_launch(void* const* d_in, const int* in_sizes, int n_in,
                              void* d_out, int out_size, void* d_ws, size_t ws_size,
                              hipStream_t stream) {
  const float* x = (const float*)d_in[0];
  const float* w_qkv = (const float*)d_in[1];
  const float* w_out = (const float*)d_in[2];
  const float* b_out = (const float*)d_in[3];
  float* out = (float*)d_out;
  char* ws = (char*)d_ws;

  unsigned short* xb    = (unsigned short*)(ws);
  unsigned short* wqkvb = (unsigned short*)(ws + 33554432);
  unsigned short* woutb = (unsigned short*)(ws + 58720256);
  unsigned short* qkvb  = (unsigned short*)(ws + 67108864);
  unsigned short* vtb   = (unsigned short*)(ws + 167772160);
  unsigned short* abuf  = xb;  // x dead after gemm1; reuse

  cvtk<<<2048, 256, 0, stream>>>(x, xb, (B_ * S_ * E_) / 4);
  cvtk<<<2048, 256, 0, stream>>>(w_qkv, wqkvb, (3 * E_ * E_) / 4);
  cvtk<<<1024, 256, 0, stream>>>(w_out, woutb, (E_ * E_) / 4);

  gemm256<0><<<768, 512, 0, stream>>>(xb, wqkvb, (void*)qkvb, nullptr,
                                      B_ * S_, 3 * E_, E_, 24);
  transpose_v<<<1024, 256, 0, stream>>>(qkvb, vtb);
  attn_fwd<<<512, 512, 0, stream>>>(qkvb, vtb, abuf);
  gemm256<1><<<256, 512, 0, stream>>>(abuf, woutb, (void*)out, b_out,
                                      B_ * S_, E_, E_, 8);
}